// Round 1
// baseline (6765.775 us; speedup 1.0000x reference)
//
#include <hip/hip_runtime.h>
#include <hip/hip_bf16.h>
#include <math.h>

constexpr int kT = 64, kB = 256, kS = 1024, kA = 32, kH = 2048;
constexpr int kH3 = 3 * kH;   // 6144
constexpr int kS2 = 2 * kS;   // 2048

typedef __hip_bfloat16 bf16;
typedef __bf16 bf16x8 __attribute__((ext_vector_type(8)));
typedef float f32x4 __attribute__((ext_vector_type(4)));

__device__ inline f32x4 mfma16(bf16x8 a, bf16x8 b, f32x4 c) {
  return __builtin_amdgcn_mfma_f32_16x16x32_bf16(a, b, c, 0, 0, 0);
}

__device__ inline void gload16(const void* g, void* l) {
  __builtin_amdgcn_global_load_lds(
      (const __attribute__((address_space(1))) void*)g,
      (__attribute__((address_space(3))) void*)l, 16, 0, 0);
}

// Stage a [ROWS][64] bf16 tile (K-contiguous rows, row stride ldK elems) into LDS.
// One issue = 256 threads x 16B = 32 rows. LDS dest is wave-uniform + lane*16.
template<int ROWS>
__device__ inline void stage_tile(const bf16* __restrict__ g, int ldK, bf16* lds) {
  const int tid = threadIdx.x;
  const int wv = tid >> 6;
#pragma unroll
  for (int i = 0; i < ROWS / 32; ++i) {
    const int idx = i * 256 + tid;      // 16B-chunk id
    const int r = idx >> 3;
    const int c = (idx & 7) << 3;
    gload16(g + (size_t)r * ldK + c, lds + (size_t)(i * 4 + wv) * 512);
  }
}

// MFMA fragment from LDS tile [*][64]: lane l -> row row0+(l&15), k = ks*32 + (l>>4)*8
__device__ inline bf16x8 ldfrag(const bf16* lds, int row0, int ks) {
  const int lane = threadIdx.x & 63;
  return *reinterpret_cast<const bf16x8*>(
      lds + (row0 + (lane & 15)) * 64 + ks * 32 + ((lane >> 4) << 3));
}

// ---------- prep kernels ----------

__global__ void k_cvt(const float* __restrict__ src, bf16* __restrict__ dst, int n) {
  int i = (blockIdx.x * 256 + threadIdx.x) * 4;
  if (i >= n) return;
  float4 v = *reinterpret_cast<const float4*>(src + i);
  dst[i + 0] = __float2bfloat16(v.x);
  dst[i + 1] = __float2bfloat16(v.y);
  dst[i + 2] = __float2bfloat16(v.z);
  dst[i + 3] = __float2bfloat16(v.w);
}

__global__ void k_cvt_belief(const float* __restrict__ src, bf16* __restrict__ dstb,
                             float* __restrict__ dstf, int n) {
  int i = (blockIdx.x * 256 + threadIdx.x) * 4;
  if (i >= n) return;
  float4 v = *reinterpret_cast<const float4*>(src + i);
  dstb[i + 0] = __float2bfloat16(v.x);
  dstb[i + 1] = __float2bfloat16(v.y);
  dstb[i + 2] = __float2bfloat16(v.z);
  dstb[i + 3] = __float2bfloat16(v.w);
  *reinterpret_cast<float4*>(dstf + i) = v;
}

// src [R][C] f32 -> dst [C][R] bf16 (LDS-tiled, both sides coalesced)
__global__ __launch_bounds__(256) void k_transpose(const float* __restrict__ src,
                                                   bf16* __restrict__ dst, int R, int C) {
  __shared__ float tile[32][33];
  const int c0 = blockIdx.x * 32, r0 = blockIdx.y * 32;
  const int tx = threadIdx.x & 31, ty = threadIdx.x >> 5;  // ty 0..7
#pragma unroll
  for (int i = 0; i < 32; i += 8)
    tile[ty + i][tx] = src[(size_t)(r0 + ty + i) * C + c0 + tx];
  __syncthreads();
#pragma unroll
  for (int i = 0; i < 32; i += 8)
    dst[(size_t)(c0 + ty + i) * R + r0 + tx] = __float2bfloat16(tile[tx][ty + i]);
}

// actb[tb][h] = b_tp[h] + sum_a actions[tb][a] * Wtpa[a][h]   (K=32)
__global__ __launch_bounds__(256) void k_actb(const float* __restrict__ actions,
                                              const float* __restrict__ Wtpa,
                                              const float* __restrict__ b_tp,
                                              bf16* __restrict__ actb) {
  __shared__ float a_s[32];
  const int tb = blockIdx.x;
  const int tid = threadIdx.x;
  if (tid < 32) a_s[tid] = actions[(size_t)tb * 32 + tid];
  __syncthreads();
#pragma unroll
  for (int j = 0; j < 8; ++j) {
    int h = j * 256 + tid;
    float acc = b_tp[h];
#pragma unroll
    for (int a = 0; a < 32; ++a) acc += a_s[a] * Wtpa[a * kH + h];
    actb[(size_t)tb * kH + h] = __float2bfloat16(acc);
  }
}

// ---------- phase A ----------

// hidden_t = relu(state @ WtpT^T + actb_t)   M=256,N=2048,K=1024, 64x64 tiles
__global__ __launch_bounds__(256) void k_hidden(const bf16* __restrict__ stateb,
                                                const bf16* __restrict__ WtpT,
                                                const bf16* __restrict__ actb_t,
                                                bf16* __restrict__ hidden_t) {
  __shared__ __align__(16) bf16 As[64 * 64];
  __shared__ __align__(16) bf16 Bs[64 * 64];
  const int m0 = blockIdx.y * 64, n0 = blockIdx.x * 64;
  const int tid = threadIdx.x, wv = tid >> 6, lane = tid & 63;
  const int l16 = lane & 15, k8 = lane >> 4;
  const int wr = (wv >> 1) * 32, wc = (wv & 1) * 32;
  f32x4 acc[2][2] = {};
  for (int kt = 0; kt < kS; kt += 64) {
    stage_tile<64>(stateb + (size_t)m0 * kS + kt, kS, As);
    stage_tile<64>(WtpT + (size_t)n0 * kS + kt, kS, Bs);
    __syncthreads();
#pragma unroll
    for (int ks = 0; ks < 2; ++ks) {
      bf16x8 a0 = ldfrag(As, wr, ks), a1 = ldfrag(As, wr + 16, ks);
      bf16x8 b0 = ldfrag(Bs, wc, ks), b1 = ldfrag(Bs, wc + 16, ks);
      acc[0][0] = mfma16(a0, b0, acc[0][0]);
      acc[0][1] = mfma16(a0, b1, acc[0][1]);
      acc[1][0] = mfma16(a1, b0, acc[1][0]);
      acc[1][1] = mfma16(a1, b1, acc[1][1]);
    }
    __syncthreads();
  }
#pragma unroll
  for (int mi = 0; mi < 2; ++mi)
#pragma unroll
    for (int ni = 0; ni < 2; ++ni)
#pragma unroll
      for (int ii = 0; ii < 4; ++ii) {
        int row = m0 + wr + mi * 16 + k8 * 4 + ii;
        int col = n0 + wc + ni * 16 + l16;
        float h = acc[mi][ni][ii] + __bfloat162float(actb_t[(size_t)row * kH + col]);
        hidden_t[(size_t)row * kH + col] = __float2bfloat16(fmaxf(h, 0.f));
      }
}

// post: mean/std col pair (n, S+n). M=256, Npair=1024, K=2048. BM=64,BN=32.
__global__ __launch_bounds__(256) void k_post(const bf16* __restrict__ hidden_t,
                                              const bf16* __restrict__ WpostT,
                                              const float* __restrict__ b_post,
                                              const float* __restrict__ eps_t,
                                              float* __restrict__ means_t,
                                              float* __restrict__ stds_t,
                                              float* __restrict__ states_t,
                                              bf16* __restrict__ stateb) {
  __shared__ __align__(16) bf16 As[64 * 64];
  __shared__ __align__(16) bf16 BsM[32 * 64];
  __shared__ __align__(16) bf16 BsS[32 * 64];
  const int m0 = blockIdx.y * 64, n0 = blockIdx.x * 32;
  const int tid = threadIdx.x, wv = tid >> 6, lane = tid & 63;
  const int l16 = lane & 15, k8 = lane >> 4;
  const int wr = (wv >> 1) * 32, wc = (wv & 1) * 16;
  f32x4 accM[2] = {}, accS[2] = {};
  for (int kt = 0; kt < kH; kt += 64) {
    stage_tile<64>(hidden_t + (size_t)m0 * kH + kt, kH, As);
    stage_tile<32>(WpostT + (size_t)n0 * kH + kt, kH, BsM);
    stage_tile<32>(WpostT + (size_t)(kS + n0) * kH + kt, kH, BsS);
    __syncthreads();
#pragma unroll
    for (int ks = 0; ks < 2; ++ks) {
      bf16x8 a0 = ldfrag(As, wr, ks), a1 = ldfrag(As, wr + 16, ks);
      bf16x8 bm = ldfrag(BsM, wc, ks);
      bf16x8 bs = ldfrag(BsS, wc, ks);
      accM[0] = mfma16(a0, bm, accM[0]);
      accM[1] = mfma16(a1, bm, accM[1]);
      accS[0] = mfma16(a0, bs, accS[0]);
      accS[1] = mfma16(a1, bs, accS[1]);
    }
    __syncthreads();
  }
#pragma unroll
  for (int mi = 0; mi < 2; ++mi)
#pragma unroll
    for (int ii = 0; ii < 4; ++ii) {
      int row = m0 + wr + mi * 16 + k8 * 4 + ii;
      int col = n0 + wc + l16;
      float mean = accM[mi][ii] + b_post[col];
      float sraw = accS[mi][ii] + b_post[kS + col];
      float sp = (sraw > 20.f) ? sraw : log1pf(expf(sraw));
      float st = mean + sp * eps_t[(size_t)row * kS + col];
      means_t[(size_t)row * kS + col] = mean;
      stds_t[(size_t)row * kS + col] = sp;
      states_t[(size_t)row * kS + col] = st;
      stateb[(size_t)row * kS + col] = __float2bfloat16(st);
    }
}

// ---------- phase B: GI = hidden_chunk @ W_ih^T + b_ih  (128x128x64 m97-style) ----------

__global__ __launch_bounds__(256) void k_gi(const bf16* __restrict__ hidden_c,
                                            const bf16* __restrict__ Wih,
                                            const float* __restrict__ b_ih,
                                            float* __restrict__ GI) {
  __shared__ __align__(16) bf16 As[128 * 64];
  __shared__ __align__(16) bf16 Bs[128 * 64];
  const int m0 = blockIdx.y * 128, n0 = blockIdx.x * 128;
  const int tid = threadIdx.x, wv = tid >> 6, lane = tid & 63;
  const int l16 = lane & 15, k8 = lane >> 4;
  const int wr = (wv >> 1) * 64, wc = (wv & 1) * 64;
  f32x4 acc[4][4] = {};
  for (int kt = 0; kt < kH; kt += 64) {
    stage_tile<128>(hidden_c + (size_t)m0 * kH + kt, kH, As);
    stage_tile<128>(Wih + (size_t)n0 * kH + kt, kH, Bs);
    __syncthreads();
#pragma unroll
    for (int ks = 0; ks < 2; ++ks) {
      bf16x8 a[4], b[4];
#pragma unroll
      for (int i = 0; i < 4; ++i) a[i] = ldfrag(As, wr + i * 16, ks);
#pragma unroll
      for (int i = 0; i < 4; ++i) b[i] = ldfrag(Bs, wc + i * 16, ks);
#pragma unroll
      for (int mi = 0; mi < 4; ++mi)
#pragma unroll
        for (int ni = 0; ni < 4; ++ni)
          acc[mi][ni] = mfma16(a[mi], b[ni], acc[mi][ni]);
    }
    __syncthreads();
  }
#pragma unroll
  for (int mi = 0; mi < 4; ++mi)
#pragma unroll
    for (int ni = 0; ni < 4; ++ni)
#pragma unroll
      for (int ii = 0; ii < 4; ++ii) {
        int row = m0 + wr + mi * 16 + k8 * 4 + ii;
        int col = n0 + wc + ni * 16 + l16;
        GI[(size_t)row * kH3 + col] = acc[mi][ni][ii] + b_ih[col];
      }
}

// ---------- phase C: gh GEMM + fused GRU epilogue ----------
// wg owns cols n0..n0+63 in each of the 3 gates (rows g*H+n of W_hh).

__global__ __launch_bounds__(256) void k_gru(const bf16* __restrict__ beliefb,
                                             const bf16* __restrict__ Whh,
                                             const float* __restrict__ b_hh,
                                             const float* __restrict__ GI_t,
                                             float* __restrict__ belief_f32,
                                             float* __restrict__ beliefs_out_t,
                                             bf16* __restrict__ beliefb_next) {
  __shared__ __align__(16) bf16 As[64 * 64];
  __shared__ __align__(16) bf16 Bs[3][64 * 64];
  const int m0 = blockIdx.y * 64, n0 = blockIdx.x * 64;
  const int tid = threadIdx.x, wv = tid >> 6, lane = tid & 63;
  const int l16 = lane & 15, k8 = lane >> 4;
  const int wr = (wv >> 1) * 32, wc = (wv & 1) * 32;
  f32x4 acc[3][2][2] = {};
  for (int kt = 0; kt < kH; kt += 64) {
    stage_tile<64>(beliefb + (size_t)m0 * kH + kt, kH, As);
#pragma unroll
    for (int g = 0; g < 3; ++g)
      stage_tile<64>(Whh + (size_t)(g * kH + n0) * kH + kt, kH, Bs[g]);
    __syncthreads();
#pragma unroll
    for (int ks = 0; ks < 2; ++ks) {
      bf16x8 a0 = ldfrag(As, wr, ks), a1 = ldfrag(As, wr + 16, ks);
#pragma unroll
      for (int g = 0; g < 3; ++g) {
        bf16x8 b0 = ldfrag(Bs[g], wc, ks), b1 = ldfrag(Bs[g], wc + 16, ks);
        acc[g][0][0] = mfma16(a0, b0, acc[g][0][0]);
        acc[g][0][1] = mfma16(a0, b1, acc[g][0][1]);
        acc[g][1][0] = mfma16(a1, b0, acc[g][1][0]);
        acc[g][1][1] = mfma16(a1, b1, acc[g][1][1]);
      }
    }
    __syncthreads();
  }
#pragma unroll
  for (int mi = 0; mi < 2; ++mi)
#pragma unroll
    for (int ni = 0; ni < 2; ++ni)
#pragma unroll
      for (int ii = 0; ii < 4; ++ii) {
        int row = m0 + wr + mi * 16 + k8 * 4 + ii;
        int col = n0 + wc + ni * 16 + l16;
        float hr = acc[0][mi][ni][ii] + b_hh[col];
        float hz = acc[1][mi][ni][ii] + b_hh[kH + col];
        float hn = acc[2][mi][ni][ii] + b_hh[2 * kH + col];
        const float* gi = GI_t + (size_t)row * kH3;
        float r = 1.f / (1.f + expf(-(gi[col] + hr)));
        float z = 1.f / (1.f + expf(-(gi[kH + col] + hz)));
        float n = tanhf(gi[2 * kH + col] + r * hn);
        float bel = belief_f32[(size_t)row * kH + col];
        float nb = (1.f - z) * n + z * bel;
        beliefs_out_t[(size_t)row * kH + col] = nb;
        belief_f32[(size_t)row * kH + col] = nb;
        beliefb_next[(size_t)row * kH + col] = __float2bfloat16(nb);
      }
}

// ---------- host ----------

extern "C" void kernel_launch(void* const* d_in, const int* in_sizes, int n_in,
                              void* d_out, int out_size, void* d_ws, size_t ws_size,
                              hipStream_t stream) {
  const float* prev_state  = (const float*)d_in[0];
  const float* actions     = (const float*)d_in[1];
  const float* prev_belief = (const float*)d_in[2];
  const float* eps         = (const float*)d_in[3];
  const float* W_ih        = (const float*)d_in[4];
  const float* W_hh        = (const float*)d_in[5];
  const float* b_ih        = (const float*)d_in[6];
  const float* b_hh        = (const float*)d_in[7];
  const float* W_tp        = (const float*)d_in[8];
  const float* b_tp        = (const float*)d_in[9];
  const float* W_post      = (const float*)d_in[10];
  const float* b_post      = (const float*)d_in[11];

  float* out_beliefs = (float*)d_out;                          // [T,B,H]
  float* out_states  = out_beliefs + (size_t)kT * kB * kH;     // [T,B,S]
  float* out_means   = out_states + (size_t)kT * kB * kS;
  float* out_stds    = out_means + (size_t)kT * kB * kS;

  size_t off = 0;
  auto alloc = [&](size_t bytes) {
    void* r = (char*)d_ws + off;
    off += (bytes + 255) & ~(size_t)255;
    return r;
  };
  bf16* Wih_b  = (bf16*)alloc((size_t)kH3 * kH * 2);
  bf16* Whh_b  = (bf16*)alloc((size_t)kH3 * kH * 2);
  bf16* WtpT   = (bf16*)alloc((size_t)kH * kS * 2);   // [H][S]
  bf16* WpostT = (bf16*)alloc((size_t)kS2 * kH * 2);  // [2S][H]
  bf16* actb   = (bf16*)alloc((size_t)kT * kB * kH * 2);
  bf16* hidden = (bf16*)alloc((size_t)kT * kB * kH * 2);
  bf16* stateb = (bf16*)alloc((size_t)kB * kS * 2);
  bf16* bb0    = (bf16*)alloc((size_t)kB * kH * 2);
  bf16* bb1    = (bf16*)alloc((size_t)kB * kH * 2);
  bf16* bb[2]  = {bb0, bb1};
  float* belief_f32 = (float*)alloc((size_t)kB * kH * 4);
  size_t base = off;
  int CH = 64;
  while (CH > 1 && base + (size_t)CH * kB * kH3 * 4 > ws_size) CH >>= 1;
  float* GI = (float*)alloc((size_t)CH * kB * kH3 * 4);

  // prep
  k_cvt<<<dim3(kH3 * kH / 1024), 256, 0, stream>>>(W_ih, Wih_b, kH3 * kH);
  k_cvt<<<dim3(kH3 * kH / 1024), 256, 0, stream>>>(W_hh, Whh_b, kH3 * kH);
  k_cvt<<<dim3(kB * kS / 1024), 256, 0, stream>>>(prev_state, stateb, kB * kS);
  k_cvt_belief<<<dim3(kB * kH / 1024), 256, 0, stream>>>(prev_belief, bb[0], belief_f32, kB * kH);
  k_transpose<<<dim3(kH / 32, kS / 32), 256, 0, stream>>>(W_tp, WtpT, kS, kH);
  k_transpose<<<dim3(kS2 / 32, kH / 32), 256, 0, stream>>>(W_post, WpostT, kH, kS2);
  k_actb<<<dim3(kT * kB), 256, 0, stream>>>(actions, W_tp + (size_t)kS * kH, b_tp, actb);

  // phase A: state/hidden chain (serial)
  for (int t = 0; t < kT; ++t) {
    k_hidden<<<dim3(kH / 64, kB / 64), 256, 0, stream>>>(
        stateb, WtpT, actb + (size_t)t * kB * kH, hidden + (size_t)t * kB * kH);
    k_post<<<dim3(kS / 32, kB / 64), 256, 0, stream>>>(
        hidden + (size_t)t * kB * kH, WpostT, b_post, eps + (size_t)t * kB * kS,
        out_means + (size_t)t * kB * kS, out_stds + (size_t)t * kB * kS,
        out_states + (size_t)t * kB * kS, stateb);
  }

  // phase B (big batched gi GEMM, chunked by ws) + phase C (belief chain)
  for (int c0 = 0; c0 < kT; c0 += CH) {
    k_gi<<<dim3(kH3 / 128, CH * kB / 128), 256, 0, stream>>>(
        hidden + (size_t)c0 * kB * kH, Wih_b, b_ih, GI);
    for (int t = c0; t < c0 + CH; ++t) {
      k_gru<<<dim3(kH / 64, kB / 64), 256, 0, stream>>>(
          bb[t & 1], Whh_b, b_hh, GI + (size_t)(t - c0) * kB * kH3, belief_f32,
          out_beliefs + (size_t)t * kB * kH, bb[(t + 1) & 1]);
    }
  }
}